// Round 9
// baseline (441.966 us; speedup 1.0000x reference)
//
#include <hip/hip_runtime.h>

#define RANK 256
#define NB 8192
#define NMAP 15625

typedef unsigned short ushort_t;
typedef short  mfma_ab __attribute__((ext_vector_type(8)));
typedef float  f32x4   __attribute__((ext_vector_type(4)));

// workspace byte offsets (total ~9.63 MB)
#define GEH_OFF   0          // 8192*256 bf16-high = 4,194,304
#define GEL_OFF   4194304    // 8192*256 bf16-low  = 4,194,304
#define WTH_OFF   8388608    // 4 mats * 256*256 bf16 = 524,288
#define WTL_OFF   8912896    // 524,288
#define INV_OFF   9437184    // 15625 int = 62,500
#define PARTS_OFF 9499712    // 128*256 f32 = 131,072
#define C2_OFF    9630784    // 256 f32

#define DD_BLOCKS 128        // edges per block = 2048 / 128 = 16

__device__ __forceinline__ float b2f(ushort_t u) {
    return __uint_as_float(((unsigned)u) << 16);
}
__device__ __forceinline__ ushort_t f2b(float f) {   // round-to-nearest-even
    unsigned u = __float_as_uint(f);
    return (ushort_t)((u + 0x7FFFu + ((u >> 16) & 1u)) >> 16);
}

__device__ __forceinline__ f32x4 mfma_bf16(mfma_ab a, mfma_ab b, f32x4 c) {
#if defined(__gfx950__)
    return __builtin_amdgcn_mfma_f32_16x16x32_bf16(a, b, c, 0, 0, 0);
#else
    (void)a; (void)b;
    return c;   // never executed on the target device (gfx950)
#endif
}

// chain-stencil on one value: (x + up?:0 + dn?:0) / (1+up+dn), row R in [0,48)
__device__ __forceinline__ float sten1(float x, float up, float dn, int R) {
    int j = R % 9;
    float fu = (j != 0) ? 1.f : 0.f;
    float fd = (j != 8) ? 1.f : 0.f;
    float sc = (fu + fd > 1.5f) ? (1.f / 3.f) : 0.5f;
    return (x + fu * up + fd * dn) * sc;
}

// ---------------------------------------------------------------- inv = -1
__global__ void k_init_inv(int* inv) {
    int i = blockIdx.x * 256 + threadIdx.x;
    if (i < NMAP) inv[i] = -1;
}

// ------------------------------------------------- inv[key_idx[b]] = b
__global__ void k_scatter(const int* key_ids, int* inv) {
    int b = blockIdx.x * 256 + threadIdx.x;
    const int* kp = key_ids + b * 6;
    int k = kp[0]*3125 + kp[1]*625 + kp[2]*125 + kp[3]*25 + kp[4]*5 + kp[5];
    inv[k] = b;
}

// ---------------- prep: split-transpose weights to [n][k] bf16 hi/lo -------
__global__ void k_prep_w(const float* __restrict__ sageW,
                         const float* __restrict__ predW1,
                         ushort_t* __restrict__ WTh,
                         ushort_t* __restrict__ WTl)
{
    const int id = blockIdx.x;
    const int mat = id >> 4, tile = id & 15;
    const int tr = tile >> 2, tc = tile & 3;
    const float* src = (mat < 3) ? (sageW + mat * 65536) : predW1;
    ushort_t* dh = WTh + mat * 65536;
    ushort_t* dl = WTl + mat * 65536;
    __shared__ float t[64][65];
    const int tid = threadIdx.x;
    const int c = tid & 63, r0 = tid >> 6;
    #pragma unroll
    for (int i = 0; i < 16; ++i) {
        int r = r0 + i * 4;
        t[r][c] = src[(tr*64 + r) * 256 + tc*64 + c];
    }
    __syncthreads();
    #pragma unroll
    for (int i = 0; i < 16; ++i) {
        int r = r0 + i * 4;
        float f = t[c][r];                       // = src[k = tr*64+c][n = tc*64+r]
        ushort_t h = f2b(f);
        dh[(tc*64 + r) * 256 + tr*64 + c] = h;   // WT[n][k]
        dl[(tc*64 + r) * 256 + tr*64 + c] = f2b(f - b2f(h));
    }
}

// ---------------- fused GraphReader: embed + 3x(GEMM->stencil->LN->ReLU) ---
// Uses agg(X)@W == stencil_rows(X@W): the chain stencil is applied to the
// MFMA C-registers via cross-lane shuffles — no LDS agg pass, no sA tiles.
// block = 512 threads (8 waves), 5 graphs = 45 rows (pad 48 = 3 M-tiles).
// wave w owns output cols [w*32, w*32+32) = 2 N-tiles of 16.
// Activations: bf16 hi/lo master (sXh/sXl) = the MFMA A operands directly.
#define GR_G 5
#define GR_ROWS 45
#define GR_RPAD 48
#define AP 264   // bf16 pitch: 528 B row stride, 16B-aligned, 2-way-free

#define LN_PART(ACC0, ACC1, MT)                                                \
    _Pragma("unroll")                                                          \
    for (int q = 0; q < 4; ++q) {                                              \
        ACC0[q] += bias0; ACC1[q] += bias1;                                    \
        float s_  = ACC0[q] + ACC1[q];                                         \
        float ss_ = ACC0[q] * ACC0[q] + ACC1[q] * ACC1[q];                     \
        _Pragma("unroll")                                                      \
        for (int mask = 1; mask <= 8; mask <<= 1) {                            \
            s_  += __shfl_xor(s_, mask, 64);                                   \
            ss_ += __shfl_xor(ss_, mask, 64);                                  \
        }                                                                      \
        const int prow_ = (MT) * 16 + q4 * 4 + q;                              \
        if (l15 == 0 && prow_ < GR_ROWS)                                       \
            sPart[prow_][wid] = make_float2(s_, ss_);                          \
    }

#define LN_WRITE(ACC0, ACC1, MT)                                               \
    _Pragma("unroll")                                                          \
    for (int q = 0; q < 4; ++q) {                                              \
        const int row_ = (MT) * 16 + q4 * 4 + q;                               \
        if (row_ < nreal) {                                                    \
            const float2 mr_ = sMV[row_];                                      \
            float v0_ = (ACC0[q] - mr_.x) * mr_.y * gv0 + bv0;                 \
            float v1_ = (ACC1[q] - mr_.x) * mr_.y * gv1 + bv1;                 \
            v0_ = fmaxf(v0_, 0.f); v1_ = fmaxf(v1_, 0.f);                      \
            const ushort_t h0_ = f2b(v0_), h1_ = f2b(v1_);                     \
            const ushort_t lo0_ = f2b(v0_ - b2f(h0_));                         \
            const ushort_t lo1_ = f2b(v1_ - b2f(h1_));                         \
            if (L < 2) {                                                       \
                sXh[row_ * AP + colb + l15]      = h0_;                        \
                sXl[row_ * AP + colb + l15]      = lo0_;                       \
                sXh[row_ * AP + colb + 16 + l15] = h1_;                        \
                sXl[row_ * AP + colb + 16 + l15] = lo1_;                       \
            } else if ((row_ % 9) == 0) {                                      \
                const int gi_ = row_ / 9;                                      \
                GEh[(b0 + gi_) * RANK + colb + l15]      = h0_;                \
                GEl[(b0 + gi_) * RANK + colb + l15]      = lo0_;               \
                GEh[(b0 + gi_) * RANK + colb + 16 + l15] = h1_;                \
                GEl[(b0 + gi_) * RANK + colb + 16 + l15] = lo1_;               \
            }                                                                  \
        }                                                                      \
    }

// stencil over one col-group's 3 M-tile accs (V0=rows 0-15, V1=16-31, V2=32-47)
#define STENCIL_COL(V0, V1, V2)                                                \
    {                                                                          \
        float ui0 = __shfl(V0[3], lane - 16), di0 = __shfl(V0[0], lane + 16);  \
        float ui1 = __shfl(V1[3], lane - 16), di1 = __shfl(V1[0], lane + 16);  \
        float ui2 = __shfl(V2[3], lane - 16), di2 = __shfl(V2[0], lane + 16);  \
        float xu1 = __shfl(V0[3], l15 + 48);  /* row 15 -> row 16's up  */     \
        float xu2 = __shfl(V1[3], l15 + 48);  /* row 31 -> row 32's up  */     \
        float xd0 = __shfl(V1[0], l15);       /* row 16 -> row 15's down */    \
        float xd1 = __shfl(V2[0], l15);       /* row 32 -> row 31's down */    \
        const int rb0 = q4 * 4, rb1 = 16 + q4 * 4, rb2 = 32 + q4 * 4;          \
        float u0 = (q4 == 0) ? 0.f : ui0;                                      \
        float d0 = (q4 == 3) ? xd0 : di0;                                      \
        float u1 = (q4 == 0) ? xu1 : ui1;                                      \
        float d1 = (q4 == 3) ? xd1 : di1;                                      \
        float u2 = (q4 == 0) ? xu2 : ui2;                                      \
        float d2 = (q4 == 3) ? 0.f : di2;                                      \
        float z00 = sten1(V0[0], u0,    V0[1], rb0 + 0);                       \
        float z01 = sten1(V0[1], V0[0], V0[2], rb0 + 1);                       \
        float z02 = sten1(V0[2], V0[1], V0[3], rb0 + 2);                       \
        float z03 = sten1(V0[3], V0[2], d0,    rb0 + 3);                       \
        float z10 = sten1(V1[0], u1,    V1[1], rb1 + 0);                       \
        float z11 = sten1(V1[1], V1[0], V1[2], rb1 + 1);                       \
        float z12 = sten1(V1[2], V1[1], V1[3], rb1 + 2);                       \
        float z13 = sten1(V1[3], V1[2], d1,    rb1 + 3);                       \
        float z20 = sten1(V2[0], u2,    V2[1], rb2 + 0);                       \
        float z21 = sten1(V2[1], V2[0], V2[2], rb2 + 1);                       \
        float z22 = sten1(V2[2], V2[1], V2[3], rb2 + 2);                       \
        float z23 = sten1(V2[3], V2[2], d2,    rb2 + 3);                       \
        V0[0] = z00; V0[1] = z01; V0[2] = z02; V0[3] = z03;                    \
        V1[0] = z10; V1[1] = z11; V1[2] = z12; V1[3] = z13;                    \
        V2[0] = z20; V2[1] = z21; V2[2] = z22; V2[3] = z23;                    \
    }

__global__ __launch_bounds__(512, 4) void k_graph_reader(
    const int* __restrict__ features,
    const float* __restrict__ emb,
    const ushort_t* __restrict__ WTh,
    const ushort_t* __restrict__ WTl,
    const float* __restrict__ sageB,
    const float* __restrict__ lnG,
    const float* __restrict__ lnB,
    ushort_t* __restrict__ GEh,
    ushort_t* __restrict__ GEl)
{
    __shared__ __align__(16) ushort_t sXh[GR_RPAD * AP];   // 25,344 B
    __shared__ __align__(16) ushort_t sXl[GR_RPAD * AP];   // 25,344 B
    __shared__ float2 sPart[GR_ROWS][8];                   //  2,880 B
    __shared__ float2 sMV[GR_ROWS];                        //    360 B
    __shared__ int sFeat[GR_ROWS];                         //    180 B

    const int tid  = threadIdx.x;
    const int wid  = tid >> 6;
    const int lane = tid & 63;
    const int q4   = lane >> 4;
    const int l15  = lane & 15;
    const int colb = wid * 32;

    const int b0    = blockIdx.x * GR_G;
    const int ngr   = min(GR_G, NB - b0);
    const int nreal = ngr * 9;         // 45 (18 in the last block)

    if (tid < GR_ROWS) sFeat[tid] = (tid < nreal) ? features[b0 * 9 + tid] : 0;
    __syncthreads();

    // embed fill + hi/lo split: 48 rows x 64 chunks(4 fp32) = 3072 tasks
    #pragma unroll
    for (int it = 0; it < 6; ++it) {
        int t = tid + it * 512;
        int row = t >> 6, c4 = t & 63;
        float4 v = make_float4(0.f, 0.f, 0.f, 0.f);
        if (row < nreal)
            v = *(const float4*)(emb + sFeat[row] * RANK + c4 * 4);
        ushort_t h0 = f2b(v.x), h1 = f2b(v.y), h2 = f2b(v.z), h3 = f2b(v.w);
        ushort_t l0 = f2b(v.x - b2f(h0)), l1 = f2b(v.y - b2f(h1));
        ushort_t l2 = f2b(v.z - b2f(h2)), l3 = f2b(v.w - b2f(h3));
        *(uint2*)(sXh + row * AP + c4 * 4) =
            make_uint2((unsigned)h0 | ((unsigned)h1 << 16),
                       (unsigned)h2 | ((unsigned)h3 << 16));
        *(uint2*)(sXl + row * AP + c4 * 4) =
            make_uint2((unsigned)l0 | ((unsigned)l1 << 16),
                       (unsigned)l2 | ((unsigned)l3 << 16));
    }

    const f32x4 vzero = {0.f, 0.f, 0.f, 0.f};

    for (int L = 0; L < 3; ++L) {
        float bias0, bias1, gv0, gv1, bv0, bv1;
        {
            int col0 = colb + l15, col1 = colb + 16 + l15;
            bias0 = sageB[L * RANK + col0]; bias1 = sageB[L * RANK + col1];
            gv0   = lnG[L * RANK + col0];   gv1   = lnG[L * RANK + col1];
            bv0   = lnB[L * RANK + col0];   bv1   = lnB[L * RANK + col1];
        }
        __syncthreads();   // sX ready (embed or previous layer write-back)

        // split GEMM Z = X@W : [48 x 256] @ [256 x 256] slice, 3 Mt x 2 Nt
        f32x4 a00 = vzero, a01 = vzero;
        f32x4 a10 = vzero, a11 = vzero;
        f32x4 a20 = vzero, a21 = vzero;
        const ushort_t* bh = WTh + L * 65536 + (colb + l15) * RANK + q4 * 8;
        const ushort_t* bl = WTl + L * 65536 + (colb + l15) * RANK + q4 * 8;
        mfma_ab B0h = *(const mfma_ab*)(bh);
        mfma_ab B0l = *(const mfma_ab*)(bl);
        mfma_ab B1h = *(const mfma_ab*)(bh + 16 * RANK);
        mfma_ab B1l = *(const mfma_ab*)(bl + 16 * RANK);
        #pragma unroll
        for (int ks = 0; ks < 8; ++ks) {
            mfma_ab nB0h, nB0l, nB1h, nB1l;
            if (ks < 7) {
                nB0h = *(const mfma_ab*)(bh + (ks + 1) * 32);
                nB0l = *(const mfma_ab*)(bl + (ks + 1) * 32);
                nB1h = *(const mfma_ab*)(bh + 16 * RANK + (ks + 1) * 32);
                nB1l = *(const mfma_ab*)(bl + 16 * RANK + (ks + 1) * 32);
            }
            const int ab = l15 * AP + ks * 32 + q4 * 8;

            mfma_ab Ah = *(const mfma_ab*)(sXh + ab);
            mfma_ab Al = *(const mfma_ab*)(sXl + ab);
            a00 = mfma_bf16(Ah, B0h, a00);
            a00 = mfma_bf16(Al, B0h, a00);
            a00 = mfma_bf16(Ah, B0l, a00);
            a01 = mfma_bf16(Ah, B1h, a01);
            a01 = mfma_bf16(Al, B1h, a01);
            a01 = mfma_bf16(Ah, B1l, a01);

            Ah = *(const mfma_ab*)(sXh + ab + 16 * AP);
            Al = *(const mfma_ab*)(sXl + ab + 16 * AP);
            a10 = mfma_bf16(Ah, B0h, a10);
            a10 = mfma_bf16(Al, B0h, a10);
            a10 = mfma_bf16(Ah, B0l, a10);
            a11 = mfma_bf16(Ah, B1h, a11);
            a11 = mfma_bf16(Al, B1h, a11);
            a11 = mfma_bf16(Ah, B1l, a11);

            Ah = *(const mfma_ab*)(sXh + ab + 32 * AP);
            Al = *(const mfma_ab*)(sXl + ab + 32 * AP);
            a20 = mfma_bf16(Ah, B0h, a20);
            a20 = mfma_bf16(Al, B0h, a20);
            a20 = mfma_bf16(Ah, B0l, a20);
            a21 = mfma_bf16(Ah, B1h, a21);
            a21 = mfma_bf16(Al, B1h, a21);
            a21 = mfma_bf16(Ah, B1l, a21);

            if (ks < 7) { B0h = nB0h; B0l = nB0l; B1h = nB1h; B1l = nB1l; }
        }

        // chain stencil in C-registers: Zagg = stencil_rows(Z)
        STENCIL_COL(a00, a10, a20)
        STENCIL_COL(a01, a11, a21)

        // bias + LN partials (C-layout: col = lane&15, row = q4*4+q)
        LN_PART(a00, a01, 0)
        LN_PART(a10, a11, 1)
        LN_PART(a20, a21, 2)
        __syncthreads();

        if (tid < GR_ROWS) {
            float s = 0.f, q = 0.f;
            #pragma unroll
            for (int w = 0; w < 8; ++w) { float2 p = sPart[tid][w]; s += p.x; q += p.y; }
            float m = s * (1.0f / 256.0f);
            float var = q * (1.0f / 256.0f) - m * m;
            if (var < 0.f) var = 0.f;
            sMV[tid] = make_float2(m, rsqrtf(var + 1e-5f));
        }
        __syncthreads();

        // normalize + ReLU; write hi/lo master (or GE split on L==2)
        LN_WRITE(a00, a01, 0)
        LN_WRITE(a10, a11, 1)
        LN_WRITE(a20, a21, 2)
    }
}

// ---------------- dd aggregation partials (deterministic) ------------------
__global__ void k_dd_agg(const int* __restrict__ dd_src,
                         const int* __restrict__ inv,
                         const ushort_t* __restrict__ GEh,
                         const ushort_t* __restrict__ GEl,
                         float* __restrict__ parts)
{
    const int c  = threadIdx.x;
    const int e0 = blockIdx.x * (2048 / DD_BLOCKS);
    float s = 0.f;
    for (int e = e0; e < e0 + (2048 / DD_BLOCKS); ++e) {
        int b = inv[dd_src[e]];
        if (b >= 0) s += b2f(GEh[b * RANK + c]) + b2f(GEl[b * RANK + c]);
    }
    parts[blockIdx.x * RANK + c] = s;
}

// ---------------- device-node vector path -> c2 ----------------------------
__global__ void k_device(const float* __restrict__ parts,
                         const float* __restrict__ aug,
                         const float* __restrict__ infoW,
                         const float* __restrict__ infoB,
                         const float* __restrict__ ddW,
                         const float* __restrict__ ddB,
                         const float* __restrict__ normG,
                         const float* __restrict__ normB,
                         const float* __restrict__ predW1,
                         const float* __restrict__ predB1,
                         float* __restrict__ c2)
{
    __shared__ float sh[RANK];
    __shared__ float sdev[RANK];
    __shared__ float sred[RANK];
    const int n = threadIdx.x;

    float agg = 0.f;
    for (int p = 0; p < DD_BLOCKS; ++p) agg += parts[p * RANK + n];
    float info = infoB[n];
    for (int j = 0; j < 5; ++j) info += aug[j] * infoW[j * RANK + n];
    sh[n] = (agg + info) * (1.0f / 2049.0f);   // (agg + self) / (deg + 1)
    __syncthreads();

    float y = ddB[n];
    for (int k = 0; k < RANK; ++k) y += sh[k] * ddW[k * RANK + n];

    sred[n] = y; __syncthreads();
    for (int off = 128; off > 0; off >>= 1) {
        if (n < off) sred[n] += sred[n + off];
        __syncthreads();
    }
    float s = sred[0]; __syncthreads();
    sred[n] = y * y; __syncthreads();
    for (int off = 128; off > 0; off >>= 1) {
        if (n < off) sred[n] += sred[n + off];
        __syncthreads();
    }
    float q = sred[0]; __syncthreads();

    float m = s * (1.0f / 256.0f);
    float var = q * (1.0f / 256.0f) - m * m;
    if (var < 0.f) var = 0.f;
    float rs = rsqrtf(var + 1e-5f);
    float dev = (y - m) * rs * normG[n] + normB[n];
    if (dev < 0.f) dev = 0.f;
    sdev[n] = dev;
    __syncthreads();

    float o = predB1[n];
    for (int k = 0; k < RANK; ++k) o += sdev[k] * predW1[(RANK + k) * RANK + n];
    c2[n] = o;
}

// ---------------- final: out = relu(GE @ W1a + c2) . W2 + b2 ---------------
// block = 128 threads (2 waves); 32 rows/block (2 M-tiles); wave w owns
// cols [w*128, w*128+128) = 8 N-tiles.
#define PRED_MFMA3(ACC, AH, AL, BH, BL)                                        \
    ACC = mfma_bf16(AH, BH, ACC);                                              \
    ACC = mfma_bf16(AL, BH, ACC);                                              \
    ACC = mfma_bf16(AH, BL, ACC);

#define PRED_N(NT, C0, C1)                                                     \
    {                                                                          \
        mfma_ab Bh_ = *(const mfma_ab*)(bh + (NT) * 16 * RANK + ks * 32);      \
        mfma_ab Bl_ = *(const mfma_ab*)(bl + (NT) * 16 * RANK + ks * 32);      \
        PRED_MFMA3(C0, A0h, A0l, Bh_, Bl_)                                     \
        PRED_MFMA3(C1, A1h, A1l, Bh_, Bl_)                                     \
    }

#define PRED_EPI(NT, C0, C1)                                                   \
    {                                                                          \
        const int col_ = colb + (NT) * 16 + l15;                               \
        const float c2v_ = c2[col_], w2v_ = predW2[col_];                      \
        op00 += fmaxf(C0[0] + c2v_, 0.f) * w2v_;                               \
        op01 += fmaxf(C0[1] + c2v_, 0.f) * w2v_;                               \
        op02 += fmaxf(C0[2] + c2v_, 0.f) * w2v_;                               \
        op03 += fmaxf(C0[3] + c2v_, 0.f) * w2v_;                               \
        op10 += fmaxf(C1[0] + c2v_, 0.f) * w2v_;                               \
        op11 += fmaxf(C1[1] + c2v_, 0.f) * w2v_;                               \
        op12 += fmaxf(C1[2] + c2v_, 0.f) * w2v_;                               \
        op13 += fmaxf(C1[3] + c2v_, 0.f) * w2v_;                               \
    }

__global__ __launch_bounds__(128, 4) void k_pred(
    const ushort_t* __restrict__ GEh,
    const ushort_t* __restrict__ GEl,
    const ushort_t* __restrict__ W1h,   // [n][k] hi
    const ushort_t* __restrict__ W1l,   // [n][k] lo
    const float* __restrict__ c2,
    const float* __restrict__ predW2,
    const float* __restrict__ predB2,
    float* __restrict__ out)
{
    __shared__ float sO[2][32];
    const int tid = threadIdx.x;
    const int wid = tid >> 6;
    const int lane = tid & 63;
    const int q4 = lane >> 4, l15 = lane & 15;
    const int colb = wid * 128;
    const int m0 = blockIdx.x * 32;

    const f32x4 vzero = {0.f, 0.f, 0.f, 0.f};
    f32x4 c00 = vzero, c01 = vzero, c02 = vzero, c03 = vzero;
    f32x4 c04 = vzero, c05 = vzero, c06 = vzero, c07 = vzero;
    f32x4 c10 = vzero, c11 = vzero, c12 = vzero, c13 = vzero;
    f32x4 c14 = vzero, c15 = vzero, c16 = vzero, c17 = vzero;

    const ushort_t* ah0 = GEh + (m0 + l15) * RANK + q4 * 8;
    const ushort_t* al0 = GEl + (m0 + l15) * RANK + q4 * 8;
    const ushort_t* ah1 = ah0 + 16 * RANK;
    const ushort_t* al1 = al0 + 16 * RANK;
    const ushort_t* bh = W1h + (colb + l15) * RANK + q4 * 8;
    const ushort_t* bl = W1l + (colb + l15) * RANK + q4 * 8;

    #pragma unroll
    for (int ks = 0; ks < 8; ++ks) {
        mfma_ab A0h = *(const mfma_ab*)(ah0 + ks * 32);
        mfma_ab A0l = *(const mfma_ab*)(al0 + ks * 32);
        mfma_ab A1h = *(const mfma_ab*)(ah1 + ks * 32);
        mfma_ab A1l = *(const mfma_ab*)(al1 + ks * 32);
        PRED_N(0, c00, c10) PRED_N(1, c01, c11)
        PRED_N(2, c02, c12) PRED_N(3, c03, c13)
        PRED_N(4, c04, c14) PRED_N(5, c05, c15)
        PRED_N(6, c06, c16) PRED_N(7, c07, c17)
    }

    float op00 = 0.f, op01 = 0.f, op02 = 0.f, op03 = 0.f;
    float op10 = 0.f, op11 = 0.f, op12 = 0.f, op13 = 0.f;
    PRED_EPI(0, c00, c10) PRED_EPI(1, c01, c11)
    PRED_EPI(2, c02, c12) PRED_EPI(3, c03, c13)
    PRED_EPI(4, c04, c14) PRED_EPI(5, c05, c15)
    PRED_EPI(6, c06, c16) PRED_EPI(7, c07, c17)

    #pragma unroll
    for (int mask = 1; mask <= 8; mask <<= 1) {
        op00 += __shfl_xor(op00, mask, 64); op01 += __shfl_xor(op01, mask, 64);
        op02 += __shfl_xor(op02, mask, 64); op03 += __shfl_xor(op03, mask, 64);
        op10 += __shfl_xor(op10, mask, 64); op11 += __shfl_xor(op11, mask, 64);
        op12 += __shfl_xor(op12, mask, 64); op13 += __shfl_xor(op13, mask, 64);
    }
    if (l15 == 0) {
        sO[wid][q4 * 4 + 0] = op00; sO[wid][q4 * 4 + 1] = op01;
        sO[wid][q4 * 4 + 2] = op02; sO[wid][q4 * 4 + 3] = op03;
        sO[wid][16 + q4 * 4 + 0] = op10; sO[wid][16 + q4 * 4 + 1] = op11;
        sO[wid][16 + q4 * 4 + 2] = op12; sO[wid][16 + q4 * 4 + 3] = op13;
    }
    __syncthreads();
    if (tid < 32) out[m0 + tid] = sO[0][tid] + sO[1][tid] + predB2[0];
}

extern "C" void kernel_launch(void* const* d_in, const int* in_sizes, int n_in,
                              void* d_out, int out_size, void* d_ws, size_t ws_size,
                              hipStream_t stream) {
    const int* features  = (const int*)d_in[0];
    const int* key_ids   = (const int*)d_in[1];
    const int* dd_src    = (const int*)d_in[4];
    const float* emb     = (const float*)d_in[5];
    const float* sageW   = (const float*)d_in[6];
    const float* sageB   = (const float*)d_in[7];
    const float* lnG     = (const float*)d_in[8];
    const float* lnB     = (const float*)d_in[9];
    const float* ddW     = (const float*)d_in[10];
    const float* ddB     = (const float*)d_in[11];
    const float* normG   = (const float*)d_in[12];
    const float* normB   = (const float*)d_in[13];
    const float* infoW   = (const float*)d_in[14];
    const float* infoB   = (const float*)d_in[15];
    const float* aug     = (const float*)d_in[16];
    const float* predW1  = (const float*)d_in[17];
    const float* predB1  = (const float*)d_in[18];
    const float* predW2  = (const float*)d_in[19];
    const float* predB2  = (const float*)d_in[20];

    char* ws = (char*)d_ws;
    ushort_t* GEh   = (ushort_t*)(ws + GEH_OFF);
    ushort_t* GEl   = (ushort_t*)(ws + GEL_OFF);
    ushort_t* WTh   = (ushort_t*)(ws + WTH_OFF);
    ushort_t* WTl   = (ushort_t*)(ws + WTL_OFF);
    int*      inv   = (int*)(ws + INV_OFF);
    float*    parts = (float*)(ws + PARTS_OFF);
    float*    c2    = (float*)(ws + C2_OFF);
    float*    outp  = (float*)d_out;

    k_init_inv<<<62, 256, 0, stream>>>(inv);
    k_scatter<<<32, 256, 0, stream>>>(key_ids, inv);
    k_prep_w<<<64, 256, 0, stream>>>(sageW, predW1, WTh, WTl);
    k_graph_reader<<<(NB + GR_G - 1) / GR_G, 512, 0, stream>>>(
        features, emb, WTh, WTl, sageB, lnG, lnB, GEh, GEl);
    k_dd_agg<<<DD_BLOCKS, 256, 0, stream>>>(dd_src, inv, GEh, GEl, parts);
    k_device<<<1, 256, 0, stream>>>(parts, aug, infoW, infoB, ddW, ddB,
                                    normG, normB, predW1, predB1, c2);
    k_pred<<<NB / 32, 128, 0, stream>>>(GEh, GEl, WTh + 3 * 65536, WTl + 3 * 65536,
                                        c2, predW2, predB2, outp);
}

// Round 10
// 416.399 us; speedup vs baseline: 1.0614x; 1.0614x over previous
//
#include <hip/hip_runtime.h>

#define RANK 256
#define NB 8192
#define NMAP 15625

typedef unsigned short ushort_t;
typedef short  mfma_ab __attribute__((ext_vector_type(8)));
typedef float  f32x4   __attribute__((ext_vector_type(4)));

// workspace byte offsets (total ~9.63 MB)
#define GEH_OFF   0          // 8192*256 bf16-high = 4,194,304
#define GEL_OFF   4194304    // 8192*256 bf16-low  = 4,194,304
#define WTH_OFF   8388608    // 4 mats * 256*256 bf16 = 524,288
#define WTL_OFF   8912896    // 524,288
#define INV_OFF   9437184    // 15625 int = 62,500
#define PARTS_OFF 9499712    // 128*256 f32 = 131,072
#define C2_OFF    9630784    // 256 f32

#define DD_BLOCKS 128        // edges per block = 2048 / 128 = 16

__device__ __forceinline__ float b2f(ushort_t u) {
    return __uint_as_float(((unsigned)u) << 16);
}
__device__ __forceinline__ ushort_t f2b(float f) {   // round-to-nearest-even
    unsigned u = __float_as_uint(f);
    return (ushort_t)((u + 0x7FFFu + ((u >> 16) & 1u)) >> 16);
}

__device__ __forceinline__ f32x4 mfma_bf16(mfma_ab a, mfma_ab b, f32x4 c) {
#if defined(__gfx950__)
    return __builtin_amdgcn_mfma_f32_16x16x32_bf16(a, b, c, 0, 0, 0);
#else
    (void)a; (void)b;
    return c;   // never executed on the target device (gfx950)
#endif
}

// chain-stencil on one value: (x + up?:0 + dn?:0) / (1+up+dn), row R in [0,48)
__device__ __forceinline__ float sten1(float x, float up, float dn, int R) {
    int j = R % 9;
    float fu = (j != 0) ? 1.f : 0.f;
    float fd = (j != 8) ? 1.f : 0.f;
    float sc = (fu + fd > 1.5f) ? (1.f / 3.f) : 0.5f;
    return (x + fu * up + fd * dn) * sc;
}

// ---------------------------------------------------------------- inv = -1
__global__ void k_init_inv(int* inv) {
    int i = blockIdx.x * 256 + threadIdx.x;
    if (i < NMAP) inv[i] = -1;
}

// ------------------------------------------------- inv[key_idx[b]] = b
__global__ void k_scatter(const int* key_ids, int* inv) {
    int b = blockIdx.x * 256 + threadIdx.x;
    const int* kp = key_ids + b * 6;
    int k = kp[0]*3125 + kp[1]*625 + kp[2]*125 + kp[3]*25 + kp[4]*5 + kp[5];
    inv[k] = b;
}

// ---------------- prep: split-transpose weights to [n][k] bf16 hi/lo -------
__global__ void k_prep_w(const float* __restrict__ sageW,
                         const float* __restrict__ predW1,
                         ushort_t* __restrict__ WTh,
                         ushort_t* __restrict__ WTl)
{
    const int id = blockIdx.x;
    const int mat = id >> 4, tile = id & 15;
    const int tr = tile >> 2, tc = tile & 3;
    const float* src = (mat < 3) ? (sageW + mat * 65536) : predW1;
    ushort_t* dh = WTh + mat * 65536;
    ushort_t* dl = WTl + mat * 65536;
    __shared__ float t[64][65];
    const int tid = threadIdx.x;
    const int c = tid & 63, r0 = tid >> 6;
    #pragma unroll
    for (int i = 0; i < 16; ++i) {
        int r = r0 + i * 4;
        t[r][c] = src[(tr*64 + r) * 256 + tc*64 + c];
    }
    __syncthreads();
    #pragma unroll
    for (int i = 0; i < 16; ++i) {
        int r = r0 + i * 4;
        float f = t[c][r];                       // = src[k = tr*64+c][n = tc*64+r]
        ushort_t h = f2b(f);
        dh[(tc*64 + r) * 256 + tr*64 + c] = h;   // WT[n][k]
        dl[(tc*64 + r) * 256 + tr*64 + c] = f2b(f - b2f(h));
    }
}

// ---------------- fused GraphReader: embed + 3x(GEMM->stencil->LN->ReLU) ---
// agg(X)@W == stencil_rows(X@W): stencil applied to MFMA C-registers via
// cross-lane shuffles. Round-10 register surgery vs round 9: no B-prefetch
// (peak B-frag pressure 32->16 VGPRs) and epilogue-deferred bias/gamma/beta
// loads — keeps peak live VGPRs under the allocator's 64 cap => no scratch.
#define GR_G 5
#define GR_ROWS 45
#define GR_RPAD 48
#define AP 264   // bf16 pitch: 528 B row stride, 16B-aligned, 2-way-free

#define LN_PART(ACC0, ACC1, MT)                                                \
    _Pragma("unroll")                                                          \
    for (int q = 0; q < 4; ++q) {                                              \
        ACC0[q] += bias0; ACC1[q] += bias1;                                    \
        float s_  = ACC0[q] + ACC1[q];                                         \
        float ss_ = ACC0[q] * ACC0[q] + ACC1[q] * ACC1[q];                     \
        _Pragma("unroll")                                                      \
        for (int mask = 1; mask <= 8; mask <<= 1) {                            \
            s_  += __shfl_xor(s_, mask, 64);                                   \
            ss_ += __shfl_xor(ss_, mask, 64);                                  \
        }                                                                      \
        const int prow_ = (MT) * 16 + q4 * 4 + q;                              \
        if (l15 == 0 && prow_ < GR_ROWS)                                       \
            sPart[prow_][wid] = make_float2(s_, ss_);                          \
    }

#define LN_WRITE(ACC0, ACC1, MT)                                               \
    _Pragma("unroll")                                                          \
    for (int q = 0; q < 4; ++q) {                                              \
        const int row_ = (MT) * 16 + q4 * 4 + q;                               \
        if (row_ < nreal) {                                                    \
            const float2 mr_ = sMV[row_];                                      \
            float v0_ = (ACC0[q] - mr_.x) * mr_.y * gv0 + bv0;                 \
            float v1_ = (ACC1[q] - mr_.x) * mr_.y * gv1 + bv1;                 \
            v0_ = fmaxf(v0_, 0.f); v1_ = fmaxf(v1_, 0.f);                      \
            const ushort_t h0_ = f2b(v0_), h1_ = f2b(v1_);                     \
            const ushort_t lo0_ = f2b(v0_ - b2f(h0_));                         \
            const ushort_t lo1_ = f2b(v1_ - b2f(h1_));                         \
            if (L < 2) {                                                       \
                sXh[row_ * AP + colb + l15]      = h0_;                        \
                sXl[row_ * AP + colb + l15]      = lo0_;                       \
                sXh[row_ * AP + colb + 16 + l15] = h1_;                        \
                sXl[row_ * AP + colb + 16 + l15] = lo1_;                       \
            } else if ((row_ % 9) == 0) {                                      \
                const int gi_ = row_ / 9;                                      \
                GEh[(b0 + gi_) * RANK + colb + l15]      = h0_;                \
                GEl[(b0 + gi_) * RANK + colb + l15]      = lo0_;               \
                GEh[(b0 + gi_) * RANK + colb + 16 + l15] = h1_;                \
                GEl[(b0 + gi_) * RANK + colb + 16 + l15] = lo1_;               \
            }                                                                  \
        }                                                                      \
    }

// stencil over one col-group's 3 M-tile accs (V0=rows 0-15, V1=16-31, V2=32-47)
#define STENCIL_COL(V0, V1, V2)                                                \
    {                                                                          \
        float ui0 = __shfl(V0[3], lane - 16), di0 = __shfl(V0[0], lane + 16);  \
        float ui1 = __shfl(V1[3], lane - 16), di1 = __shfl(V1[0], lane + 16);  \
        float ui2 = __shfl(V2[3], lane - 16), di2 = __shfl(V2[0], lane + 16);  \
        float xu1 = __shfl(V0[3], l15 + 48);  /* row 15 -> row 16's up  */     \
        float xu2 = __shfl(V1[3], l15 + 48);  /* row 31 -> row 32's up  */     \
        float xd0 = __shfl(V1[0], l15);       /* row 16 -> row 15's down */    \
        float xd1 = __shfl(V2[0], l15);       /* row 32 -> row 31's down */    \
        const int rb0 = q4 * 4, rb1 = 16 + q4 * 4, rb2 = 32 + q4 * 4;          \
        float u0 = (q4 == 0) ? 0.f : ui0;                                      \
        float d0 = (q4 == 3) ? xd0 : di0;                                      \
        float u1 = (q4 == 0) ? xu1 : ui1;                                      \
        float d1 = (q4 == 3) ? xd1 : di1;                                      \
        float u2 = (q4 == 0) ? xu2 : ui2;                                      \
        float d2 = (q4 == 3) ? 0.f : di2;                                      \
        float z00 = sten1(V0[0], u0,    V0[1], rb0 + 0);                       \
        float z01 = sten1(V0[1], V0[0], V0[2], rb0 + 1);                       \
        float z02 = sten1(V0[2], V0[1], V0[3], rb0 + 2);                       \
        float z03 = sten1(V0[3], V0[2], d0,    rb0 + 3);                       \
        float z10 = sten1(V1[0], u1,    V1[1], rb1 + 0);                       \
        float z11 = sten1(V1[1], V1[0], V1[2], rb1 + 1);                       \
        float z12 = sten1(V1[2], V1[1], V1[3], rb1 + 2);                       \
        float z13 = sten1(V1[3], V1[2], d1,    rb1 + 3);                       \
        float z20 = sten1(V2[0], u2,    V2[1], rb2 + 0);                       \
        float z21 = sten1(V2[1], V2[0], V2[2], rb2 + 1);                       \
        float z22 = sten1(V2[2], V2[1], V2[3], rb2 + 2);                       \
        float z23 = sten1(V2[3], V2[2], d2,    rb2 + 3);                       \
        V0[0] = z00; V0[1] = z01; V0[2] = z02; V0[3] = z03;                    \
        V1[0] = z10; V1[1] = z11; V1[2] = z12; V1[3] = z13;                    \
        V2[0] = z20; V2[1] = z21; V2[2] = z22; V2[3] = z23;                    \
    }

__global__ __launch_bounds__(512, 4) void k_graph_reader(
    const int* __restrict__ features,
    const float* __restrict__ emb,
    const ushort_t* __restrict__ WTh,
    const ushort_t* __restrict__ WTl,
    const float* __restrict__ sageB,
    const float* __restrict__ lnG,
    const float* __restrict__ lnB,
    ushort_t* __restrict__ GEh,
    ushort_t* __restrict__ GEl)
{
    __shared__ __align__(16) ushort_t sXh[GR_RPAD * AP];   // 25,344 B
    __shared__ __align__(16) ushort_t sXl[GR_RPAD * AP];   // 25,344 B
    __shared__ float2 sPart[GR_ROWS][8];                   //  2,880 B
    __shared__ float2 sMV[GR_ROWS];                        //    360 B
    __shared__ int sFeat[GR_ROWS];                         //    180 B

    const int tid  = threadIdx.x;
    const int wid  = tid >> 6;
    const int lane = tid & 63;
    const int q4   = lane >> 4;
    const int l15  = lane & 15;
    const int colb = wid * 32;

    const int b0    = blockIdx.x * GR_G;
    const int ngr   = min(GR_G, NB - b0);
    const int nreal = ngr * 9;         // 45 (18 in the last block)

    if (tid < GR_ROWS) sFeat[tid] = (tid < nreal) ? features[b0 * 9 + tid] : 0;
    __syncthreads();

    // embed fill + hi/lo split: 48 rows x 64 chunks(4 fp32) = 3072 tasks
    #pragma unroll
    for (int it = 0; it < 6; ++it) {
        int t = tid + it * 512;
        int row = t >> 6, c4 = t & 63;
        float4 v = make_float4(0.f, 0.f, 0.f, 0.f);
        if (row < nreal)
            v = *(const float4*)(emb + sFeat[row] * RANK + c4 * 4);
        ushort_t h0 = f2b(v.x), h1 = f2b(v.y), h2 = f2b(v.z), h3 = f2b(v.w);
        ushort_t l0 = f2b(v.x - b2f(h0)), l1 = f2b(v.y - b2f(h1));
        ushort_t l2 = f2b(v.z - b2f(h2)), l3 = f2b(v.w - b2f(h3));
        *(uint2*)(sXh + row * AP + c4 * 4) =
            make_uint2((unsigned)h0 | ((unsigned)h1 << 16),
                       (unsigned)h2 | ((unsigned)h3 << 16));
        *(uint2*)(sXl + row * AP + c4 * 4) =
            make_uint2((unsigned)l0 | ((unsigned)l1 << 16),
                       (unsigned)l2 | ((unsigned)l3 << 16));
    }

    const f32x4 vzero = {0.f, 0.f, 0.f, 0.f};

    for (int L = 0; L < 3; ++L) {
        __syncthreads();   // sX ready (embed or previous layer write-back)

        // split GEMM Z = X@W : [48 x 256] @ [256 x 256] slice, 3 Mt x 2 Nt
        // B-frags loaded per-ks (no prefetch: keeps peak VGPRs < 64, r10)
        f32x4 a00 = vzero, a01 = vzero;
        f32x4 a10 = vzero, a11 = vzero;
        f32x4 a20 = vzero, a21 = vzero;
        const ushort_t* bh = WTh + L * 65536 + (colb + l15) * RANK + q4 * 8;
        const ushort_t* bl = WTl + L * 65536 + (colb + l15) * RANK + q4 * 8;
        #pragma unroll
        for (int ks = 0; ks < 8; ++ks) {
            mfma_ab B0h = *(const mfma_ab*)(bh + ks * 32);
            mfma_ab B0l = *(const mfma_ab*)(bl + ks * 32);
            mfma_ab B1h = *(const mfma_ab*)(bh + 16 * RANK + ks * 32);
            mfma_ab B1l = *(const mfma_ab*)(bl + 16 * RANK + ks * 32);
            const int ab = l15 * AP + ks * 32 + q4 * 8;

            mfma_ab Ah = *(const mfma_ab*)(sXh + ab);
            mfma_ab Al = *(const mfma_ab*)(sXl + ab);
            a00 = mfma_bf16(Ah, B0h, a00);
            a00 = mfma_bf16(Al, B0h, a00);
            a00 = mfma_bf16(Ah, B0l, a00);
            a01 = mfma_bf16(Ah, B1h, a01);
            a01 = mfma_bf16(Al, B1h, a01);
            a01 = mfma_bf16(Ah, B1l, a01);

            Ah = *(const mfma_ab*)(sXh + ab + 16 * AP);
            Al = *(const mfma_ab*)(sXl + ab + 16 * AP);
            a10 = mfma_bf16(Ah, B0h, a10);
            a10 = mfma_bf16(Al, B0h, a10);
            a10 = mfma_bf16(Ah, B0l, a10);
            a11 = mfma_bf16(Ah, B1h, a11);
            a11 = mfma_bf16(Al, B1h, a11);
            a11 = mfma_bf16(Ah, B1l, a11);

            Ah = *(const mfma_ab*)(sXh + ab + 32 * AP);
            Al = *(const mfma_ab*)(sXl + ab + 32 * AP);
            a20 = mfma_bf16(Ah, B0h, a20);
            a20 = mfma_bf16(Al, B0h, a20);
            a20 = mfma_bf16(Ah, B0l, a20);
            a21 = mfma_bf16(Ah, B1h, a21);
            a21 = mfma_bf16(Al, B1h, a21);
            a21 = mfma_bf16(Ah, B1l, a21);
        }

        // chain stencil in C-registers: Zagg = stencil_rows(Z)
        STENCIL_COL(a00, a10, a20)
        STENCIL_COL(a01, a11, a21)

        // epilogue scalars loaded only now (short live range, r10)
        float bias0, bias1, gv0, gv1, bv0, bv1;
        {
            int col0 = colb + l15, col1 = colb + 16 + l15;
            bias0 = sageB[L * RANK + col0]; bias1 = sageB[L * RANK + col1];
            gv0   = lnG[L * RANK + col0];   gv1   = lnG[L * RANK + col1];
            bv0   = lnB[L * RANK + col0];   bv1   = lnB[L * RANK + col1];
        }

        // bias + LN partials (C-layout: col = lane&15, row = q4*4+q)
        LN_PART(a00, a01, 0)
        LN_PART(a10, a11, 1)
        LN_PART(a20, a21, 2)
        __syncthreads();

        if (tid < GR_ROWS) {
            float s = 0.f, q = 0.f;
            #pragma unroll
            for (int w = 0; w < 8; ++w) { float2 p = sPart[tid][w]; s += p.x; q += p.y; }
            float m = s * (1.0f / 256.0f);
            float var = q * (1.0f / 256.0f) - m * m;
            if (var < 0.f) var = 0.f;
            sMV[tid] = make_float2(m, rsqrtf(var + 1e-5f));
        }
        __syncthreads();

        // normalize + ReLU; write hi/lo master (or GE split on L==2)
        LN_WRITE(a00, a01, 0)
        LN_WRITE(a10, a11, 1)
        LN_WRITE(a20, a21, 2)
    }
}

// ---------------- dd aggregation partials (deterministic) ------------------
__global__ void k_dd_agg(const int* __restrict__ dd_src,
                         const int* __restrict__ inv,
                         const ushort_t* __restrict__ GEh,
                         const ushort_t* __restrict__ GEl,
                         float* __restrict__ parts)
{
    const int c  = threadIdx.x;
    const int e0 = blockIdx.x * (2048 / DD_BLOCKS);
    float s = 0.f;
    for (int e = e0; e < e0 + (2048 / DD_BLOCKS); ++e) {
        int b = inv[dd_src[e]];
        if (b >= 0) s += b2f(GEh[b * RANK + c]) + b2f(GEl[b * RANK + c]);
    }
    parts[blockIdx.x * RANK + c] = s;
}

// ---------------- device-node vector path -> c2 ----------------------------
__global__ void k_device(const float* __restrict__ parts,
                         const float* __restrict__ aug,
                         const float* __restrict__ infoW,
                         const float* __restrict__ infoB,
                         const float* __restrict__ ddW,
                         const float* __restrict__ ddB,
                         const float* __restrict__ normG,
                         const float* __restrict__ normB,
                         const float* __restrict__ predW1,
                         const float* __restrict__ predB1,
                         float* __restrict__ c2)
{
    __shared__ float sh[RANK];
    __shared__ float sdev[RANK];
    __shared__ float sred[RANK];
    const int n = threadIdx.x;

    float agg = 0.f;
    for (int p = 0; p < DD_BLOCKS; ++p) agg += parts[p * RANK + n];
    float info = infoB[n];
    for (int j = 0; j < 5; ++j) info += aug[j] * infoW[j * RANK + n];
    sh[n] = (agg + info) * (1.0f / 2049.0f);   // (agg + self) / (deg + 1)
    __syncthreads();

    float y = ddB[n];
    for (int k = 0; k < RANK; ++k) y += sh[k] * ddW[k * RANK + n];

    sred[n] = y; __syncthreads();
    for (int off = 128; off > 0; off >>= 1) {
        if (n < off) sred[n] += sred[n + off];
        __syncthreads();
    }
    float s = sred[0]; __syncthreads();
    sred[n] = y * y; __syncthreads();
    for (int off = 128; off > 0; off >>= 1) {
        if (n < off) sred[n] += sred[n + off];
        __syncthreads();
    }
    float q = sred[0]; __syncthreads();

    float m = s * (1.0f / 256.0f);
    float var = q * (1.0f / 256.0f) - m * m;
    if (var < 0.f) var = 0.f;
    float rs = rsqrtf(var + 1e-5f);
    float dev = (y - m) * rs * normG[n] + normB[n];
    if (dev < 0.f) dev = 0.f;
    sdev[n] = dev;
    __syncthreads();

    float o = predB1[n];
    for (int k = 0; k < RANK; ++k) o += sdev[k] * predW1[(RANK + k) * RANK + n];
    c2[n] = o;
}

// ---------------- final: out = relu(GE @ W1a + c2) . W2 + b2 ---------------
// block = 128 threads (2 waves); 32 rows/block (2 M-tiles); wave w owns
// cols [w*128, w*128+128) = 8 N-tiles.
#define PRED_MFMA3(ACC, AH, AL, BH, BL)                                        \
    ACC = mfma_bf16(AH, BH, ACC);                                              \
    ACC = mfma_bf16(AL, BH, ACC);                                              \
    ACC = mfma_bf16(AH, BL, ACC);

#define PRED_N(NT, C0, C1)                                                     \
    {                                                                          \
        mfma_ab Bh_ = *(const mfma_ab*)(bh + (NT) * 16 * RANK + ks * 32);      \
        mfma_ab Bl_ = *(const mfma_ab*)(bl + (NT) * 16 * RANK + ks * 32);      \
        PRED_MFMA3(C0, A0h, A0l, Bh_, Bl_)                                     \
        PRED_MFMA3(C1, A1h, A1l, Bh_, Bl_)                                     \
    }

#define PRED_EPI(NT, C0, C1)                                                   \
    {                                                                          \
        const int col_ = colb + (NT) * 16 + l15;                               \
        const float c2v_ = c2[col_], w2v_ = predW2[col_];                      \
        op00 += fmaxf(C0[0] + c2v_, 0.f) * w2v_;                               \
        op01 += fmaxf(C0[1] + c2v_, 0.f) * w2v_;                               \
        op02 += fmaxf(C0[2] + c2v_, 0.f) * w2v_;                               \
        op03 += fmaxf(C0[3] + c2v_, 0.f) * w2v_;                               \
        op10 += fmaxf(C1[0] + c2v_, 0.f) * w2v_;                               \
        op11 += fmaxf(C1[1] + c2v_, 0.f) * w2v_;                               \
        op12 += fmaxf(C1[2] + c2v_, 0.f) * w2v_;                               \
        op13 += fmaxf(C1[3] + c2v_, 0.f) * w2v_;                               \
    }

__global__ __launch_bounds__(128, 4) void k_pred(
    const ushort_t* __restrict__ GEh,
    const ushort_t* __restrict__ GEl,
    const ushort_t* __restrict__ W1h,   // [n][k] hi
    const ushort_t* __restrict__ W1l,   // [n][k] lo
    const float* __restrict__ c2,
    const float* __restrict__ predW2,
    const float* __restrict__ predB2,
    float* __restrict__ out)
{
    __shared__ float sO[2][32];
    const int tid = threadIdx.x;
    const int wid = tid >> 6;
    const int lane = tid & 63;
    const int q4 = lane >> 4, l15 = lane & 15;
    const int colb = wid * 128;
    const int m0 = blockIdx.x * 32;

    const f32x4 vzero = {0.f, 0.f, 0.f, 0.f};
    f32x4 c00 = vzero, c01 = vzero, c02 = vzero, c03 = vzero;
    f32x4 c04 = vzero, c05 = vzero, c06 = vzero, c07 = vzero;
    f32x4 c10 = vzero, c11 = vzero, c12 = vzero, c13 = vzero;
    f32x4 c14 = vzero, c15 = vzero, c16 = vzero, c17 = vzero;

    const ushort_t* ah0 = GEh + (m0 + l15) * RANK + q4 * 8;
    const ushort_t* al0 = GEl + (m0 + l15) * RANK + q4 * 8;
    const ushort_t* ah1 = ah0 + 16 * RANK;
    const ushort_t* al1 = al0 + 16 * RANK;
    const ushort_t* bh = W1h + (colb + l15) * RANK + q4 * 8;
    const ushort_t* bl = W1l + (colb + l15) * RANK + q4 * 8;

    #pragma unroll
    for (int ks = 0; ks < 8; ++ks) {
        mfma_ab A0h = *(const mfma_ab*)(ah0 + ks * 32);
        mfma_ab A0l = *(const mfma_ab*)(al0 + ks * 32);
        mfma_ab A1h = *(const mfma_ab*)(ah1 + ks * 32);
        mfma_ab A1l = *(const mfma_ab*)(al1 + ks * 32);
        PRED_N(0, c00, c10) PRED_N(1, c01, c11)
        PRED_N(2, c02, c12) PRED_N(3, c03, c13)
        PRED_N(4, c04, c14) PRED_N(5, c05, c15)
        PRED_N(6, c06, c16) PRED_N(7, c07, c17)
    }

    float op00 = 0.f, op01 = 0.f, op02 = 0.f, op03 = 0.f;
    float op10 = 0.f, op11 = 0.f, op12 = 0.f, op13 = 0.f;
    PRED_EPI(0, c00, c10) PRED_EPI(1, c01, c11)
    PRED_EPI(2, c02, c12) PRED_EPI(3, c03, c13)
    PRED_EPI(4, c04, c14) PRED_EPI(5, c05, c15)
    PRED_EPI(6, c06, c16) PRED_EPI(7, c07, c17)

    #pragma unroll
    for (int mask = 1; mask <= 8; mask <<= 1) {
        op00 += __shfl_xor(op00, mask, 64); op01 += __shfl_xor(op01, mask, 64);
        op02 += __shfl_xor(op02, mask, 64); op03 += __shfl_xor(op03, mask, 64);
        op10 += __shfl_xor(op10, mask, 64); op11 += __shfl_xor(op11, mask, 64);
        op12 += __shfl_xor(op12, mask, 64); op13 += __shfl_xor(op13, mask, 64);
    }
    if (l15 == 0) {
        sO[wid][q4 * 4 + 0] = op00; sO[wid][q4 * 4 + 1] = op01;
        sO[wid][q4 * 4 + 2] = op02; sO[wid][q4 * 4 + 3] = op03;
        sO[wid][16 + q4 * 4 + 0] = op10; sO[wid][16 + q4 * 4 + 1] = op11;
        sO[wid][16 + q4 * 4 + 2] = op12; sO[wid][16 + q4 * 4 + 3] = op13;
    }
    __syncthreads();
    if (tid < 32) out[m0 + tid] = sO[0][tid] + sO[1][tid] + predB2[0];
}

extern "C" void kernel_launch(void* const* d_in, const int* in_sizes, int n_in,
                              void* d_out, int out_size, void* d_ws, size_t ws_size,
                              hipStream_t stream) {
    const int* features  = (const int*)d_in[0];
    const int* key_ids   = (const int*)d_in[1];
    const int* dd_src    = (const int*)d_in[4];
    const float* emb     = (const float*)d_in[5];
    const float* sageW   = (const float*)d_in[6];
    const float* sageB   = (const float*)d_in[7];
    const float* lnG     = (const float*)d_in[8];
    const float* lnB     = (const float*)d_in[9];
    const float* ddW     = (const float*)d_in[10];
    const float* ddB     = (const float*)d_in[11];
    const float* normG   = (const float*)d_in[12];
    const float* normB   = (const float*)d_in[13];
    const float* infoW   = (const float*)d_in[14];
    const float* infoB   = (const float*)d_in[15];
    const float* aug     = (const float*)d_in[16];
    const float* predW1  = (const float*)d_in[17];
    const float* predB1  = (const float*)d_in[18];
    const float* predW2  = (const float*)d_in[19];
    const float* predB2  = (const float*)d_in[20];

    char* ws = (char*)d_ws;
    ushort_t* GEh   = (ushort_t*)(ws + GEH_OFF);
    ushort_t* GEl   = (ushort_t*)(ws + GEL_OFF);
    ushort_t* WTh   = (ushort_t*)(ws + WTH_OFF);
    ushort_t* WTl   = (ushort_t*)(ws + WTL_OFF);
    int*      inv   = (int*)(ws + INV_OFF);
    float*    parts = (float*)(ws + PARTS_OFF);
    float*    c2    = (float*)(ws + C2_OFF);
    float*    outp  = (float*)d_out;

    k_init_inv<<<62, 256, 0, stream>>>(inv);
    k_scatter<<<32, 256, 0, stream>>>(key_ids, inv);
    k_prep_w<<<64, 256, 0, stream>>>(sageW, predW1, WTh, WTl);
    k_graph_reader<<<(NB + GR_G - 1) / GR_G, 512, 0, stream>>>(
        features, emb, WTh, WTl, sageB, lnG, lnB, GEh, GEl);
    k_dd_agg<<<DD_BLOCKS, 256, 0, stream>>>(dd_src, inv, GEh, GEl, parts);
    k_device<<<1, 256, 0, stream>>>(parts, aug, infoW, infoB, ddW, ddB,
                                    normG, normB, predW1, predB1, c2);
    k_pred<<<NB / 32, 128, 0, stream>>>(GEh, GEl, WTh + 3 * 65536, WTl + 3 * 65536,
                                        c2, predW2, predB2, outp);
}